// Round 1
// baseline (184.971 us; speedup 1.0000x reference)
//
#include <hip/hip_runtime.h>

#define B_   16
#define S_   128
#define R_   1024
#define KIN  25
#define H_   128
#define MID  256
#define INDIM 154   // 25 + 128 + 1
#define KP   160    // padded K (5 blocks of 32)
#define ROWS 64     // rows per block

typedef _Float16 half8 __attribute__((ext_vector_type(8)));
typedef float    f32x4 __attribute__((ext_vector_type(4)));

// ---------------------------------------------------------------------------
// prep: Wc = Wh1@Wh2 stored transposed+padded as WT[128][160] fp16,
//       wo = Wo1@Wo2 stored padded as wo[160] fp32.
// ---------------------------------------------------------------------------
__global__ void prep_kernel(const float* __restrict__ Wo1, const float* __restrict__ Wo2,
                            const float* __restrict__ Wh1, const float* __restrict__ Wh2,
                            _Float16* __restrict__ WT, float* __restrict__ wo)
{
    int j = blockIdx.x * 256 + threadIdx.x;
    if (j < H_ * KP) {
        int n = j / KP, k = j - n * KP;
        float acc = 0.f;
        if (k < INDIM)
            for (int m = 0; m < MID; ++m)
                acc += Wh1[k * MID + m] * Wh2[m * H_ + n];
        WT[n * KP + k] = (_Float16)acc;
    } else if (j < H_ * KP + KP) {
        int k = j - H_ * KP;
        float acc = 0.f;
        if (k < INDIM)
            for (int m = 0; m < MID; ++m)
                acc += Wo1[k * MID + m] * Wo2[m];
        wo[k] = acc;
    }
}

// ---------------------------------------------------------------------------
// main persistent kernel: 256 blocks x 256 threads; block owns 64 rows for all
// 128 steps. A (inter matrix, fp16) double-buffered in LDS; weights in regs.
// ---------------------------------------------------------------------------
__global__ __launch_bounds__(256, 1) void rnn_main(
    const float* __restrict__ x, const float* __restrict__ hidden,
    const float* __restrict__ cost, const _Float16* __restrict__ WT,
    const float* __restrict__ wo, float* __restrict__ outs,
    float* __restrict__ hfin)
{
    __shared__ _Float16 A[2][ROWS][KP];        // 40,960 B
    __shared__ float    partials[2][4][ROWS];  //  2,048 B

    const int t    = threadIdx.x;
    const int lane = t & 63, wave = t >> 6;
    const int l15  = lane & 15, lg = lane >> 4;
    const int wm   = wave >> 1, wn = wave & 1;
    const int bidx = blockIdx.x;
    const int b    = bidx >> 4;               // 16 blocks per batch element
    const int r0   = (bidx & 15) << 6;        // 64-row slab within R

    // ---- B fragments (weights) into registers, once ----
    // b-frag elem u = B[kb*32 + lg*8 + u][wn*64 + nt*16 + l15] = WT[n][k...]
    half8 bf[4][5];
#pragma unroll
    for (int nt = 0; nt < 4; ++nt)
#pragma unroll
        for (int kb = 0; kb < 5; ++kb)
            bf[nt][kb] = *reinterpret_cast<const half8*>(
                &WT[(wn * 64 + nt * 16 + l15) * KP + kb * 32 + lg * 8]);

    // wo segment for out-partials: wave = k-quarter (40 each), lane = row
    float woq[40];
#pragma unroll
    for (int i = 0; i < 40; ++i) woq[i] = wo[wave * 40 + i];

    // x scatter coords (fixed per thread): element e = t + i*256 of 64x25 slab
    int xrow[7], xk[7];
#pragma unroll
    for (int i = 0; i < 7; ++i) {
        int e = t + i * 256;
        xrow[i] = e / 25;
        xk[i]   = e - 25 * xrow[i];
    }

    // ---- init ----
    if (t < ROWS) {
#pragma unroll
        for (int k = INDIM; k < KP; ++k) {   // zero K-padding in both buffers
            A[0][t][k] = (_Float16)0.f;
            A[1][t][k] = (_Float16)0.f;
        }
    }
    {   // h(0)
        const float* hsrc = hidden + ((long)(b * R_ + r0)) * H_;
#pragma unroll
        for (int i = 0; i < 32; ++i) {       // 64*128 / 256
            int e = t + i * 256;
            A[0][e >> 7][25 + (e & 127)] = (_Float16)hsrc[e];
        }
    }
    {   // x(0), c(0)
        const float* xs = x + ((long)(b * S_) * R_ + r0) * KIN;
#pragma unroll
        for (int i = 0; i < 7; ++i) {
            int e = t + i * 256;
            if (e < ROWS * KIN) A[0][xrow[i]][xk[i]] = (_Float16)xs[e];
        }
        if (t < ROWS) A[0][t][153] = (_Float16)cost[b * S_];
    }
    __syncthreads();

    const f32x4 fz = {0.f, 0.f, 0.f, 0.f};
    f32x4 acc[2][4];
    const float* xbase = x + ((long)(b * S_) * R_ + r0) * KIN;

    for (int s = 0; s < S_; ++s) {
        const int cur = s & 1, nxt = cur ^ 1;

        // store out(s-1): reduce partials written last iteration
        if (s > 0 && t < ROWS) {
            outs[(b * S_ + (s - 1)) * R_ + r0 + t] =
                partials[nxt][0][t] + partials[nxt][1][t] +
                partials[nxt][2][t] + partials[nxt][3][t];
        }

        // prefetch x,c for s+1 (latency hidden under MFMA phase)
        float xr2[7];
        float cr2 = 0.f;
        const bool havenext = (s + 1 < S_);
        if (havenext) {
            const float* xs = xbase + (long)(s + 1) * R_ * KIN;
#pragma unroll
            for (int i = 0; i < 7; ++i) {
                int e = t + i * 256;
                xr2[i] = (e < ROWS * KIN) ? xs[e] : 0.f;
            }
            cr2 = cost[b * S_ + s + 1];
        }

        // ---- GEMM: h_new[64x128] = A[cur][64x160] @ Wc[160x128] ----
#pragma unroll
        for (int mt = 0; mt < 2; ++mt)
#pragma unroll
            for (int nt = 0; nt < 4; ++nt) acc[mt][nt] = fz;

#pragma unroll
        for (int kb = 0; kb < 5; ++kb) {
            half8 a0 = *reinterpret_cast<const half8*>(
                &A[cur][wm * 32 + l15][kb * 32 + lg * 8]);
            half8 a1 = *reinterpret_cast<const half8*>(
                &A[cur][wm * 32 + 16 + l15][kb * 32 + lg * 8]);
#pragma unroll
            for (int nt = 0; nt < 4; ++nt) {
                acc[0][nt] = __builtin_amdgcn_mfma_f32_16x16x32_f16(a0, bf[nt][kb], acc[0][nt], 0, 0, 0);
                acc[1][nt] = __builtin_amdgcn_mfma_f32_16x16x32_f16(a1, bf[nt][kb], acc[1][nt], 0, 0, 0);
            }
        }

        // ---- out partial for step s: row = lane, k-quarter = wave ----
        {
            float p = 0.f;
#pragma unroll
            for (int v = 0; v < 5; ++v) {
                half8 av = *reinterpret_cast<const half8*>(
                    &A[cur][lane][wave * 40 + v * 8]);
#pragma unroll
                for (int u = 0; u < 8; ++u) p += (float)av[u] * woq[v * 8 + u];
            }
            partials[cur][wave][lane] = p;
        }

        // ---- write A[nxt]: h(s+1) from acc, x(s+1), c(s+1) ----
        if (havenext) {
#pragma unroll
            for (int mt = 0; mt < 2; ++mt)
#pragma unroll
                for (int nt = 0; nt < 4; ++nt)
#pragma unroll
                    for (int j = 0; j < 4; ++j) {
                        int row = wm * 32 + mt * 16 + lg * 4 + j;  // D: row=(l>>4)*4+reg
                        int col = wn * 64 + nt * 16 + l15;         // D: col=l&15
                        A[nxt][row][25 + col] = (_Float16)acc[mt][nt][j];
                    }
#pragma unroll
            for (int i = 0; i < 7; ++i) {
                int e = t + i * 256;
                if (e < ROWS * KIN) A[nxt][xrow[i]][xk[i]] = (_Float16)xr2[i];
            }
            if (t < ROWS) A[nxt][t][153] = (_Float16)cr2;
        }
        __syncthreads();
    }

    // out(S-1)
    if (t < ROWS) {
        outs[(b * S_ + (S_ - 1)) * R_ + r0 + t] =
            partials[1][0][t] + partials[1][1][t] +
            partials[1][2][t] + partials[1][3][t];
    }
    // h_final straight from fp32 accumulators
#pragma unroll
    for (int mt = 0; mt < 2; ++mt)
#pragma unroll
        for (int nt = 0; nt < 4; ++nt)
#pragma unroll
            for (int j = 0; j < 4; ++j) {
                int row = wm * 32 + mt * 16 + lg * 4 + j;
                int col = wn * 64 + nt * 16 + l15;
                hfin[((long)(b * R_ + r0 + row)) * H_ + col] = acc[mt][nt][j];
            }
}

// ---------------------------------------------------------------------------
extern "C" void kernel_launch(void* const* d_in, const int* in_sizes, int n_in,
                              void* d_out, int out_size, void* d_ws, size_t ws_size,
                              hipStream_t stream)
{
    const float* x      = (const float*)d_in[0];
    const float* hidden = (const float*)d_in[1];
    const float* cost   = (const float*)d_in[2];
    const float* Wo1    = (const float*)d_in[3];
    const float* Wo2    = (const float*)d_in[4];
    const float* Wh1    = (const float*)d_in[5];
    const float* Wh2    = (const float*)d_in[6];

    float* outs = (float*)d_out;                    // [B,S,R]
    float* hfin = outs + (long)B_ * S_ * R_;        // [B,R,H]

    _Float16* WT = (_Float16*)d_ws;                 // [128][160] fp16
    float*    wo = (float*)((char*)d_ws + (size_t)H_ * KP * sizeof(_Float16)); // [160]

    int prep_jobs = H_ * KP + KP;                   // 20,640
    prep_kernel<<<(prep_jobs + 255) / 256, 256, 0, stream>>>(Wo1, Wo2, Wh1, Wh2, WT, wo);
    rnn_main<<<256, 256, 0, stream>>>(x, hidden, cost, WT, wo, outs, hfin);
}

// Round 3
// 137.321 us; speedup vs baseline: 1.3470x; 1.3470x over previous
//
#include <hip/hip_runtime.h>

#define B_   16
#define S_   128
#define R_   1024
#define KIN  25
#define H_   128
#define MID  256
#define KP   160    // weight K stride (global, padded to 5x32)
#define KL   168    // LDS inter row stride (bank spread: 84 dw % 32 = 20)
#define ROWS 32     // rows per block

typedef _Float16 half8  __attribute__((ext_vector_type(8)));
typedef __fp16   h16x4  __attribute__((ext_vector_type(4)));
typedef __fp16   h16x2  __attribute__((ext_vector_type(2)));
typedef float    f32x4  __attribute__((ext_vector_type(4)));

// inter k-order is PERMUTED: [h(0..127) | x(128..152) | c(153) | pad]
__device__ __forceinline__ int orig_k(int kp) {
    if (kp < H_)        return KIN + kp;   // h dims (orig 25..152)
    if (kp < H_ + KIN)  return kp - H_;    // x dims (orig 0..24)
    if (kp == H_ + KIN) return H_ + KIN;   // c (orig 153)
    return -1;                             // zero pad
}

// ---------------------------------------------------------------------------
// prep: WTP[i=h-out][kp] = Wc[orig_k(kp)][i] fp16 ; woP[kp] fp16
// ---------------------------------------------------------------------------
__global__ void prep_kernel(const float* __restrict__ Wo1, const float* __restrict__ Wo2,
                            const float* __restrict__ Wh1, const float* __restrict__ Wh2,
                            _Float16* __restrict__ WTP, _Float16* __restrict__ woP)
{
    int j = blockIdx.x * 256 + threadIdx.x;
    if (j < H_ * KP) {
        int i = j / KP, kp = j - i * KP;
        int ok = orig_k(kp);
        float acc = 0.f;
        if (ok >= 0)
            for (int m = 0; m < MID; ++m)
                acc += Wh1[ok * MID + m] * Wh2[m * H_ + i];
        WTP[i * KP + kp] = (_Float16)acc;
    } else if (j < H_ * KP + KP) {
        int kp = j - H_ * KP;
        int ok = orig_k(kp);
        float acc = 0.f;
        if (ok >= 0)
            for (int m = 0; m < MID; ++m)
                acc += Wo1[ok * MID + m] * Wo2[m];
        woP[kp] = (_Float16)acc;
    }
}

// ---------------------------------------------------------------------------
// main: 512 blocks x 256 thr (2 blocks/CU). Block owns 32 rows for all steps.
// Swapped MFMA: D = WcT(A-op, regs) @ interT(B-op, LDS row-major read).
// D lane layout: col=l15 -> inter row m ; row=lg*4+j -> h-col -> packed b64 write.
// ---------------------------------------------------------------------------
__global__ __launch_bounds__(256, 2) void rnn_main(
    const float* __restrict__ x, const float* __restrict__ hidden,
    const float* __restrict__ cost, const _Float16* __restrict__ WTP,
    const _Float16* __restrict__ woP, float* __restrict__ outs,
    float* __restrict__ hfin)
{
    __shared__ _Float16 A[2][ROWS][KL];   // 21,504 B

    const int t    = threadIdx.x;
    const int lane = t & 63, wave = t >> 6;
    const int l15  = lane & 15, lg = lane >> 4;
    const int wm   = wave & 1;            // m-tile (16 rows)
    const int wi   = wave >> 1;           // h-half (64 cols)
    const int b    = blockIdx.x >> 5;
    const int r0   = (blockIdx.x & 31) << 5;

    const int xrow = t >> 3, xseg = t & 7;  // x loader mapping

    // ---- weights into registers (A-operand: lane holds WTP[i=l15][k contig]) ----
    half8 af[4][5];
#pragma unroll
    for (int it = 0; it < 4; ++it)
#pragma unroll
        for (int kb = 0; kb < 5; ++kb)
            af[it][kb] = *reinterpret_cast<const half8*>(
                &WTP[(wi * 64 + it * 16 + l15) * KP + kb * 32 + lg * 8]);

    half8 wz;
#pragma unroll
    for (int u = 0; u < 8; ++u) wz[u] = (_Float16)0.f;
    half8 wof[5];
#pragma unroll
    for (int kb = 0; kb < 5; ++kb) {
        half8 w = *reinterpret_cast<const half8*>(&woP[kb * 32 + lg * 8]);
        wof[kb] = (l15 == 0) ? w : wz;    // out tile: A row 0 = wo, rows 1..15 = 0
    }

    // ---- init LDS buffer 0 ----
    if (t < ROWS) {
#pragma unroll
        for (int k = H_ + KIN + 1; k < KL; ++k) {
            A[0][t][k] = (_Float16)0.f;
            A[1][t][k] = (_Float16)0.f;
        }
    }
    {   // h(0): thread covers row xrow, 16 cols at xseg*16
        const float4* h4 = reinterpret_cast<const float4*>(
            hidden + ((long)(b * R_ + r0 + xrow)) * H_ + xseg * 16);
#pragma unroll
        for (int q = 0; q < 2; ++q) {
            float4 p0 = h4[q * 2], p1 = h4[q * 2 + 1];
            h16x2 c0 = __builtin_amdgcn_cvt_pkrtz(p0.x, p0.y);
            h16x2 c1 = __builtin_amdgcn_cvt_pkrtz(p0.z, p0.w);
            h16x2 c2 = __builtin_amdgcn_cvt_pkrtz(p1.x, p1.y);
            h16x2 c3 = __builtin_amdgcn_cvt_pkrtz(p1.z, p1.w);
            h16x4 v0; v0[0]=c0[0]; v0[1]=c0[1]; v0[2]=c1[0]; v0[3]=c1[1];
            h16x4 v1; v1[0]=c2[0]; v1[1]=c2[1]; v1[2]=c3[0]; v1[3]=c3[1];
            *reinterpret_cast<h16x4*>(&A[0][xrow][xseg * 16 + q * 8])     = v0;
            *reinterpret_cast<h16x4*>(&A[0][xrow][xseg * 16 + q * 8 + 4]) = v1;
        }
    }
    {   // x(0), c(0)
        const float* xs = x + (((long)(b * S_)) * R_ + r0 + xrow) * KIN;
        if (xseg < 6) {
            h16x2 ca = __builtin_amdgcn_cvt_pkrtz(xs[xseg*4],   xs[xseg*4+1]);
            h16x2 cb = __builtin_amdgcn_cvt_pkrtz(xs[xseg*4+2], xs[xseg*4+3]);
            h16x4 v; v[0]=ca[0]; v[1]=ca[1]; v[2]=cb[0]; v[3]=cb[1];
            *reinterpret_cast<h16x4*>(&A[0][xrow][H_ + xseg * 4]) = v;
        } else if (xseg == 6) {
            h16x2 ca = __builtin_amdgcn_cvt_pkrtz(xs[24], cost[b * S_]);
            *reinterpret_cast<h16x2*>(&A[0][xrow][H_ + 24]) = ca;
        }
    }
    __syncthreads();

    const f32x4 fz = {0.f, 0.f, 0.f, 0.f};
    f32x4 acc[4], acc_o;

    for (int s = 0; s < S_; ++s) {
        const int cur = s & 1, nxt = cur ^ 1;
        const bool havenext = (s + 1 < S_);

        // prefetch x(s+1), c(s+1) — latency hides under MFMA phase
        float px0 = 0.f, px1 = 0.f, px2 = 0.f, px3 = 0.f, pc = 0.f;
        if (havenext) {
            const float* xs = x + (((long)(b * S_ + s + 1)) * R_ + r0 + xrow) * KIN;
            if (xseg < 6) {
                px0 = xs[xseg*4];   px1 = xs[xseg*4+1];
                px2 = xs[xseg*4+2]; px3 = xs[xseg*4+3];
            } else if (xseg == 6) {
                px0 = xs[24];
                pc  = cost[b * S_ + s + 1];
            }
        }

        acc[0] = fz; acc[1] = fz; acc[2] = fz; acc[3] = fz; acc_o = fz;
#pragma unroll
        for (int kb = 0; kb < 5; ++kb) {
            half8 bf = *reinterpret_cast<const half8*>(
                &A[cur][wm * 16 + l15][kb * 32 + lg * 8]);
#pragma unroll
            for (int it = 0; it < 4; ++it)
                acc[it] = __builtin_amdgcn_mfma_f32_16x16x32_f16(af[it][kb], bf, acc[it], 0, 0, 0);
            if (wi == 0)
                acc_o = __builtin_amdgcn_mfma_f32_16x16x32_f16(wof[kb], bf, acc_o, 0, 0, 0);
        }

        // out(s): D row 0 lives in lanes lg==0, reg 0; 16 lanes -> 64 B store
        if (wi == 0 && lg == 0)
            outs[((long)(b * S_ + s)) * R_ + r0 + wm * 16 + l15] = acc_o[0];

        if (havenext) {
            // h(s+1): 4 packed b64 writes (4 consecutive h-cols per lane)
#pragma unroll
            for (int it = 0; it < 4; ++it) {
                h16x2 lo = __builtin_amdgcn_cvt_pkrtz(acc[it][0], acc[it][1]);
                h16x2 hi = __builtin_amdgcn_cvt_pkrtz(acc[it][2], acc[it][3]);
                h16x4 v; v[0]=lo[0]; v[1]=lo[1]; v[2]=hi[0]; v[3]=hi[1];
                *reinterpret_cast<h16x4*>(
                    &A[nxt][wm * 16 + l15][wi * 64 + it * 16 + lg * 4]) = v;
            }
            // x(s+1), c(s+1)
            if (xseg < 6) {
                h16x2 ca = __builtin_amdgcn_cvt_pkrtz(px0, px1);
                h16x2 cb = __builtin_amdgcn_cvt_pkrtz(px2, px3);
                h16x4 v; v[0]=ca[0]; v[1]=ca[1]; v[2]=cb[0]; v[3]=cb[1];
                *reinterpret_cast<h16x4*>(&A[nxt][xrow][H_ + xseg * 4]) = v;
            } else if (xseg == 6) {
                h16x2 ca = __builtin_amdgcn_cvt_pkrtz(px0, pc);
                *reinterpret_cast<h16x2*>(&A[nxt][xrow][H_ + 24]) = ca;
            }
        }
        __syncthreads();
    }

    // h_final from fp32 accumulators (lane: row wm*16+l15, 4 cols at wi*64+it*16+lg*4)
#pragma unroll
    for (int it = 0; it < 4; ++it) {
        *reinterpret_cast<f32x4*>(
            &hfin[((long)(b * R_ + r0 + wm * 16 + l15)) * H_ + wi * 64 + it * 16 + lg * 4])
            = acc[it];
    }
}

// ---------------------------------------------------------------------------
extern "C" void kernel_launch(void* const* d_in, const int* in_sizes, int n_in,
                              void* d_out, int out_size, void* d_ws, size_t ws_size,
                              hipStream_t stream)
{
    const float* x      = (const float*)d_in[0];
    const float* hidden = (const float*)d_in[1];
    const float* cost   = (const float*)d_in[2];
    const float* Wo1    = (const float*)d_in[3];
    const float* Wo2    = (const float*)d_in[4];
    const float* Wh1    = (const float*)d_in[5];
    const float* Wh2    = (const float*)d_in[6];

    float* outs = (float*)d_out;                    // [B,S,R]
    float* hfin = outs + (long)B_ * S_ * R_;        // [B,R,H]

    _Float16* WTP = (_Float16*)d_ws;                             // [128][160]
    _Float16* woP = WTP + (size_t)H_ * KP;                       // [160]

    int prep_jobs = H_ * KP + KP;
    prep_kernel<<<(prep_jobs + 255) / 256, 256, 0, stream>>>(Wo1, Wo2, Wh1, Wh2, WTP, woP);
    rnn_main<<<512, 256, 0, stream>>>(x, hidden, cost, WTP, woP, outs, hfin);
}